// Round 6
// baseline (321.977 us; speedup 1.0000x reference)
//
#include <hip/hip_runtime.h>

#define NROWS 8192   // N == M == 8192
#define DDIM  512
#define OUTN  8192

typedef int   i32x4 __attribute__((ext_vector_type(4)));
typedef int   i32x8 __attribute__((ext_vector_type(8)));
typedef float f32x4 __attribute__((ext_vector_type(4)));

// ---------------------------------------------------------------------------
// Prepass: fp32 -> fp8 e4m3 (OCP) + fp32 row sq-norms, emitting the fp8 data
// DIRECTLY IN MFMA FRAGMENT LAYOUT so the GEMM needs no LDS and no barriers.
//
// Fragment layout for mfma_scale_f32_16x16x128_f8f6f4 (A and B identical):
// lane l holds row (l&15), k-bytes (l>>4)*32 .. +32 of a 128-k window.
// Storage: off(group, h, l, b) = group*8192 + h*2048 + l*32 + b
//   where group = row>>4 (16-row group), h = k-window (0..3), b = 0..31.
// A wave's 64 lanes then read 2 KB contiguous per (group,h): 2x dwordx4/lane.
// ---------------------------------------------------------------------------
__global__ void __launch_bounds__(256)
rbf_prep(const float* __restrict__ x, const float* __restrict__ y,
         unsigned char* __restrict__ xs, unsigned char* __restrict__ ys,
         float* __restrict__ x2, float* __restrict__ y2) {
    int wave = (blockIdx.x * blockDim.x + threadIdx.x) >> 6;  // 0..16383
    int lane = threadIdx.x & 63;

    const float* src;
    unsigned char* dst;
    float* nrm;
    int row;
    if (wave < NROWS) { src = x; dst = xs; nrm = x2; row = wave; }
    else              { src = y; dst = ys; nrm = y2; row = wave - NROWS; }

    const float* p = src + (size_t)row * DDIM + lane * 8;
    float4 v0 = *(const float4*)(p);
    float4 v1 = *(const float4*)(p + 4);

    float s = v0.x * v0.x + v0.y * v0.y + v0.z * v0.z + v0.w * v0.w
            + v1.x * v1.x + v1.y * v1.y + v1.z * v1.z + v1.w * v1.w;

    int lo = __builtin_amdgcn_cvt_pk_fp8_f32(v0.x, v0.y, 0, false);
    lo     = __builtin_amdgcn_cvt_pk_fp8_f32(v0.z, v0.w, lo, true);
    int hi = __builtin_amdgcn_cvt_pk_fp8_f32(v1.x, v1.y, 0, false);
    hi     = __builtin_amdgcn_cvt_pk_fp8_f32(v1.z, v1.w, hi, true);

    int h  = lane >> 4;
    int kq = (lane >> 2) & 3;
    int kb = (lane & 3) * 8;
    size_t off = (size_t)(row >> 4) * 8192 + h * 2048 + kq * 512
               + (row & 15) * 32 + kb;
    *(int2*)(dst + off) = make_int2(lo, hi);

#pragma unroll
    for (int off2 = 32; off2 > 0; off2 >>= 1) s += __shfl_down(s, off2, 64);
    if (lane == 0) nrm[row] = s;
}

// ---------------------------------------------------------------------------
// Fused GEMM + RBF epilogue, MX-fp8 (scale = 1.0), BARRIER-FREE + register
// software pipeline: window h+1's 16 fragment loads are issued BEFORE window
// h's MFMAs (ping-pong register buffers, full unroll), so only window 0's
// L2 latency is exposed. No LDS, no __syncthreads — waves fully independent.
// 128x128 block tile, 4 waves (2x2), wave = 4x4 of 16x16x128 MFMAs.
// ---------------------------------------------------------------------------
__global__ void __launch_bounds__(256)
rbf_gemm(const unsigned char* __restrict__ xs,
         const unsigned char* __restrict__ ys,
         const float* __restrict__ x2, const float* __restrict__ y2,
         const float* __restrict__ gamma, float* __restrict__ out) {
    const int tid  = threadIdx.x;
    const int lane = tid & 63;
    const int w    = tid >> 6;        // wave 0..3
    const int wm   = w & 1;           // wave row (0..1)
    const int wn   = w >> 1;          // wave col (0..1)

    const int bm = blockIdx.x & 63;   // fast-varying -> consecutive blocks
    const int bn = blockIdx.x >> 6;   //   share the B tile (L2 locality)
    const int row0 = bm * 128;
    const int col0 = bn * 128;

    f32x4 acc[4][4] = {};

    // fragment base: group (bm*8 + wm*4 + mi), window h, lane*32
    const unsigned char* abase = xs + (size_t)(bm * 8 + wm * 4) * 8192 + lane * 32;
    const unsigned char* bbase = ys + (size_t)(bn * 8 + wn * 4) * 8192 + lane * 32;

    i32x8 fa[2][4], fb[2][4];

    // prologue: load window 0
#pragma unroll
    for (int mi = 0; mi < 4; ++mi) {
        const unsigned char* p = abase + mi * 8192;
        i32x4 lo = *(const i32x4*)(p);
        i32x4 hi = *(const i32x4*)(p + 16);
        fa[0][mi] = __builtin_shufflevector(lo, hi, 0, 1, 2, 3, 4, 5, 6, 7);
    }
#pragma unroll
    for (int ni = 0; ni < 4; ++ni) {
        const unsigned char* p = bbase + ni * 8192;
        i32x4 lo = *(const i32x4*)(p);
        i32x4 hi = *(const i32x4*)(p + 16);
        fb[0][ni] = __builtin_shufflevector(lo, hi, 0, 1, 2, 3, 4, 5, 6, 7);
    }

#pragma unroll
    for (int h = 0; h < 4; ++h) {
        const int c = h & 1, n = c ^ 1;
        if (h < 3) {   // prefetch window h+1 before consuming window h
#pragma unroll
            for (int mi = 0; mi < 4; ++mi) {
                const unsigned char* p = abase + mi * 8192 + (h + 1) * 2048;
                i32x4 lo = *(const i32x4*)(p);
                i32x4 hi = *(const i32x4*)(p + 16);
                fa[n][mi] = __builtin_shufflevector(lo, hi, 0, 1, 2, 3, 4, 5, 6, 7);
            }
#pragma unroll
            for (int ni = 0; ni < 4; ++ni) {
                const unsigned char* p = bbase + ni * 8192 + (h + 1) * 2048;
                i32x4 lo = *(const i32x4*)(p);
                i32x4 hi = *(const i32x4*)(p + 16);
                fb[n][ni] = __builtin_shufflevector(lo, hi, 0, 1, 2, 3, 4, 5, 6, 7);
            }
        }
#pragma unroll
        for (int mi = 0; mi < 4; ++mi)
#pragma unroll
            for (int ni = 0; ni < 4; ++ni)
                acc[mi][ni] = __builtin_amdgcn_mfma_scale_f32_16x16x128_f8f6f4(
                    fa[c][mi], fb[c][ni], acc[mi][ni],
                    0, 0,          // cbsz/blgp = fp8 e4m3
                    0, 0x7F,       // A scale = 1.0 (E8M0 127)
                    0, 0x7F);      // B scale = 1.0
    }

    // Epilogue: out[r][c] = exp(-g*(x2[r]+y2[c]-2*xy))
    // C/D layout (16x16): col = lane&15, row = (lane>>4)*4 + reg.
    // Plain scalar stores; L2 write-back merges the 64 B segments into lines.
    const float g = gamma[0];
#pragma unroll
    for (int mi = 0; mi < 4; ++mi) {
        const int rbase = row0 + wm * 64 + mi * 16 + (lane >> 4) * 4;
        float xn[4];
#pragma unroll
        for (int r = 0; r < 4; ++r) xn[r] = x2[rbase + r];
#pragma unroll
        for (int ni = 0; ni < 4; ++ni) {
            const int col = col0 + wn * 64 + ni * 16 + (lane & 15);
            const float yn = y2[col];
            float* op = out + (size_t)rbase * OUTN + col;
#pragma unroll
            for (int r = 0; r < 4; ++r) {
                float s = xn[r] + yn - 2.0f * acc[mi][ni][r];
                op[(size_t)r * OUTN] = __expf(-g * s);
            }
        }
    }
}

extern "C" void kernel_launch(void* const* d_in, const int* in_sizes, int n_in,
                              void* d_out, int out_size, void* d_ws, size_t ws_size,
                              hipStream_t stream) {
    const float* x     = (const float*)d_in[0];
    const float* y     = (const float*)d_in[1];
    const float* gamma = (const float*)d_in[2];
    float* out = (float*)d_out;

    // workspace: xs (4 MB, swizzled fp8) | ys (4 MB) | x2 (32 KB) | y2 (32 KB)
    char* ws = (char*)d_ws;
    unsigned char* xs = (unsigned char*)ws;
    unsigned char* ys = (unsigned char*)(ws + (size_t)NROWS * DDIM);
    float* x2 = (float*)(ws + (size_t)NROWS * DDIM * 2);
    float* y2 = (float*)(ws + (size_t)NROWS * DDIM * 2 + NROWS * 4);

    rbf_prep<<<4096, 256, 0, stream>>>(x, y, xs, ys, x2, y2);
    rbf_gemm<<<4096, 256, 0, stream>>>(xs, ys, x2, y2, gamma, out);
}

// Round 7
// 318.455 us; speedup vs baseline: 1.0111x; 1.0111x over previous
//
#include <hip/hip_runtime.h>

#define NROWS 8192   // N == M == 8192
#define DDIM  512
#define OUTN  8192

typedef int   i32x4 __attribute__((ext_vector_type(4)));
typedef int   i32x8 __attribute__((ext_vector_type(8)));
typedef float f32x4 __attribute__((ext_vector_type(4)));

// ---------------------------------------------------------------------------
// Prepass: fp32 -> fp8 e4m3 (OCP) + fp32 row sq-norms, emitting the fp8 data
// DIRECTLY IN MFMA FRAGMENT LAYOUT so the GEMM needs no LDS and no barriers.
//
// Fragment layout for mfma_scale_f32_16x16x128_f8f6f4 (A and B identical):
// lane l holds row (l&15), k-bytes (l>>4)*32 .. +32 of a 128-k window.
// Storage: off(group, h, l, b) = group*8192 + h*2048 + l*32 + b
//   where group = row>>4 (16-row group), h = k-window (0..3), b = 0..31.
// A wave's 64 lanes then read 2 KB contiguous per (group,h): 2x dwordx4/lane.
// ---------------------------------------------------------------------------
__global__ void __launch_bounds__(256)
rbf_prep(const float* __restrict__ x, const float* __restrict__ y,
         unsigned char* __restrict__ xs, unsigned char* __restrict__ ys,
         float* __restrict__ x2, float* __restrict__ y2) {
    int wave = (blockIdx.x * blockDim.x + threadIdx.x) >> 6;  // 0..16383
    int lane = threadIdx.x & 63;

    const float* src;
    unsigned char* dst;
    float* nrm;
    int row;
    if (wave < NROWS) { src = x; dst = xs; nrm = x2; row = wave; }
    else              { src = y; dst = ys; nrm = y2; row = wave - NROWS; }

    const float* p = src + (size_t)row * DDIM + lane * 8;
    float4 v0 = *(const float4*)(p);
    float4 v1 = *(const float4*)(p + 4);

    float s = v0.x * v0.x + v0.y * v0.y + v0.z * v0.z + v0.w * v0.w
            + v1.x * v1.x + v1.y * v1.y + v1.z * v1.z + v1.w * v1.w;

    int lo = __builtin_amdgcn_cvt_pk_fp8_f32(v0.x, v0.y, 0, false);
    lo     = __builtin_amdgcn_cvt_pk_fp8_f32(v0.z, v0.w, lo, true);
    int hi = __builtin_amdgcn_cvt_pk_fp8_f32(v1.x, v1.y, 0, false);
    hi     = __builtin_amdgcn_cvt_pk_fp8_f32(v1.z, v1.w, hi, true);

    int h  = lane >> 4;
    int kq = (lane >> 2) & 3;
    int kb = (lane & 3) * 8;
    size_t off = (size_t)(row >> 4) * 8192 + h * 2048 + kq * 512
               + (row & 15) * 32 + kb;
    *(int2*)(dst + off) = make_int2(lo, hi);

#pragma unroll
    for (int off2 = 32; off2 > 0; off2 >>= 1) s += __shfl_down(s, off2, 64);
    if (lane == 0) nrm[row] = s;
}

// ---------------------------------------------------------------------------
// Fused GEMM + RBF epilogue, MX-fp8 (scale = 1.0), BARRIER-FREE (R5 structure
// — the compiler schedules cross-window load hoisting on its own; explicit
// ping-pong pipelining in R6 regressed via register pressure).
// One change vs R5: __launch_bounds__(256, 3) to cap VGPRs ~170 and force
// >=3 waves/SIMD (12 waves/CU) for latency hiding of L2 fragment loads and
// epilogue stores.
// 128x128 block tile, 4 waves (2x2), wave = 4x4 of 16x16x128 MFMAs.
// ---------------------------------------------------------------------------
__global__ void __launch_bounds__(256, 3)
rbf_gemm(const unsigned char* __restrict__ xs,
         const unsigned char* __restrict__ ys,
         const float* __restrict__ x2, const float* __restrict__ y2,
         const float* __restrict__ gamma, float* __restrict__ out) {
    const int tid  = threadIdx.x;
    const int lane = tid & 63;
    const int w    = tid >> 6;        // wave 0..3
    const int wm   = w & 1;           // wave row (0..1)
    const int wn   = w >> 1;          // wave col (0..1)

    const int bm = blockIdx.x & 63;   // fast-varying -> consecutive blocks
    const int bn = blockIdx.x >> 6;   //   share the B tile (L2 locality)
    const int row0 = bm * 128;
    const int col0 = bn * 128;

    f32x4 acc[4][4] = {};

    // fragment base: group (bm*8 + wm*4 + mi), window h, lane*32
    const unsigned char* abase = xs + (size_t)(bm * 8 + wm * 4) * 8192 + lane * 32;
    const unsigned char* bbase = ys + (size_t)(bn * 8 + wn * 4) * 8192 + lane * 32;

#pragma unroll 2
    for (int h = 0; h < 4; ++h) {
        i32x8 af[4], bfr[4];
#pragma unroll
        for (int mi = 0; mi < 4; ++mi) {
            const unsigned char* p = abase + mi * 8192 + h * 2048;
            i32x4 lo = *(const i32x4*)(p);
            i32x4 hi = *(const i32x4*)(p + 16);
            af[mi] = __builtin_shufflevector(lo, hi, 0, 1, 2, 3, 4, 5, 6, 7);
        }
#pragma unroll
        for (int ni = 0; ni < 4; ++ni) {
            const unsigned char* p = bbase + ni * 8192 + h * 2048;
            i32x4 lo = *(const i32x4*)(p);
            i32x4 hi = *(const i32x4*)(p + 16);
            bfr[ni] = __builtin_shufflevector(lo, hi, 0, 1, 2, 3, 4, 5, 6, 7);
        }
#pragma unroll
        for (int mi = 0; mi < 4; ++mi)
#pragma unroll
            for (int ni = 0; ni < 4; ++ni)
                acc[mi][ni] = __builtin_amdgcn_mfma_scale_f32_16x16x128_f8f6f4(
                    af[mi], bfr[ni], acc[mi][ni],
                    0, 0,          // cbsz/blgp = fp8 e4m3
                    0, 0x7F,       // A scale = 1.0 (E8M0 127)
                    0, 0x7F);      // B scale = 1.0
    }

    // Epilogue: out[r][c] = exp(-g*(x2[r]+y2[c]-2*xy))
    // C/D layout (16x16): col = lane&15, row = (lane>>4)*4 + reg.
    // Plain scalar stores; L2 write-back merges the 64 B segments into lines.
    const float g = gamma[0];
#pragma unroll
    for (int mi = 0; mi < 4; ++mi) {
        const int rbase = row0 + wm * 64 + mi * 16 + (lane >> 4) * 4;
        float xn[4];
#pragma unroll
        for (int r = 0; r < 4; ++r) xn[r] = x2[rbase + r];
#pragma unroll
        for (int ni = 0; ni < 4; ++ni) {
            const int col = col0 + wn * 64 + ni * 16 + (lane & 15);
            const float yn = y2[col];
            float* op = out + (size_t)rbase * OUTN + col;
#pragma unroll
            for (int r = 0; r < 4; ++r) {
                float s = xn[r] + yn - 2.0f * acc[mi][ni][r];
                op[(size_t)r * OUTN] = __expf(-g * s);
            }
        }
    }
}

extern "C" void kernel_launch(void* const* d_in, const int* in_sizes, int n_in,
                              void* d_out, int out_size, void* d_ws, size_t ws_size,
                              hipStream_t stream) {
    const float* x     = (const float*)d_in[0];
    const float* y     = (const float*)d_in[1];
    const float* gamma = (const float*)d_in[2];
    float* out = (float*)d_out;

    // workspace: xs (4 MB, swizzled fp8) | ys (4 MB) | x2 (32 KB) | y2 (32 KB)
    char* ws = (char*)d_ws;
    unsigned char* xs = (unsigned char*)ws;
    unsigned char* ys = (unsigned char*)(ws + (size_t)NROWS * DDIM);
    float* x2 = (float*)(ws + (size_t)NROWS * DDIM * 2);
    float* y2 = (float*)(ws + (size_t)NROWS * DDIM * 2 + NROWS * 4);

    rbf_prep<<<4096, 256, 0, stream>>>(x, y, xs, ys, x2, y2);
    rbf_gemm<<<4096, 256, 0, stream>>>(xs, ys, x2, y2, gamma, out);
}

// Round 8
// 312.357 us; speedup vs baseline: 1.0308x; 1.0195x over previous
//
#include <hip/hip_runtime.h>

#define NROWS 8192   // N == M == 8192
#define DDIM  512
#define OUTN  8192

typedef int   i32x4 __attribute__((ext_vector_type(4)));
typedef int   i32x8 __attribute__((ext_vector_type(8)));
typedef float f32x4 __attribute__((ext_vector_type(4)));

// ---------------------------------------------------------------------------
// Prepass: fp32 -> fp8 e4m3 (OCP) + fp32 row sq-norms, emitting the fp8 data
// DIRECTLY IN MFMA FRAGMENT LAYOUT so the GEMM needs no LDS and no barriers.
//
// Fragment layout for mfma_scale_f32_16x16x128_f8f6f4 (A and B identical):
// lane l holds row (l&15), k-bytes (l>>4)*32 .. +32 of a 128-k window.
// Storage: off(group, h, l, b) = group*8192 + h*2048 + l*32 + b
//   where group = row>>4 (16-row group), h = k-window (0..3), b = 0..31.
// A wave's 64 lanes then read 2 KB contiguous per (group,h): 2x dwordx4/lane.
// ---------------------------------------------------------------------------
__global__ void __launch_bounds__(256)
rbf_prep(const float* __restrict__ x, const float* __restrict__ y,
         unsigned char* __restrict__ xs, unsigned char* __restrict__ ys,
         float* __restrict__ x2, float* __restrict__ y2) {
    int wave = (blockIdx.x * blockDim.x + threadIdx.x) >> 6;  // 0..16383
    int lane = threadIdx.x & 63;

    const float* src;
    unsigned char* dst;
    float* nrm;
    int row;
    if (wave < NROWS) { src = x; dst = xs; nrm = x2; row = wave; }
    else              { src = y; dst = ys; nrm = y2; row = wave - NROWS; }

    const float* p = src + (size_t)row * DDIM + lane * 8;
    float4 v0 = *(const float4*)(p);
    float4 v1 = *(const float4*)(p + 4);

    float s = v0.x * v0.x + v0.y * v0.y + v0.z * v0.z + v0.w * v0.w
            + v1.x * v1.x + v1.y * v1.y + v1.z * v1.z + v1.w * v1.w;

    int lo = __builtin_amdgcn_cvt_pk_fp8_f32(v0.x, v0.y, 0, false);
    lo     = __builtin_amdgcn_cvt_pk_fp8_f32(v0.z, v0.w, lo, true);
    int hi = __builtin_amdgcn_cvt_pk_fp8_f32(v1.x, v1.y, 0, false);
    hi     = __builtin_amdgcn_cvt_pk_fp8_f32(v1.z, v1.w, hi, true);

    int h  = lane >> 4;
    int kq = (lane >> 2) & 3;
    int kb = (lane & 3) * 8;
    size_t off = (size_t)(row >> 4) * 8192 + h * 2048 + kq * 512
               + (row & 15) * 32 + kb;
    *(int2*)(dst + off) = make_int2(lo, hi);

#pragma unroll
    for (int off2 = 32; off2 > 0; off2 >>= 1) s += __shfl_down(s, off2, 64);
    if (lane == 0) nrm[row] = s;
}

// ---------------------------------------------------------------------------
// Fused GEMM + RBF epilogue, MX-fp8 (scale = 1.0), BARRIER-FREE.
// R5 structure — best measured configuration:
//   - inputs pre-swizzled to fragment layout, fragments loaded straight from
//     global (L2-resident working set) via global_load_dwordx4; no LDS, no
//     __syncthreads, no barrier drain.
//   - default launch bounds: (256,3) cap forced spills (R7, +7us); manual
//     ping-pong pipelining blew registers (R6, +10us); compiler's own
//     scheduler handles cross-window load hoisting best.
// 128x128 block tile, 4 waves (2x2), wave = 4x4 of 16x16x128 MFMAs.
// ---------------------------------------------------------------------------
__global__ void __launch_bounds__(256)
rbf_gemm(const unsigned char* __restrict__ xs,
         const unsigned char* __restrict__ ys,
         const float* __restrict__ x2, const float* __restrict__ y2,
         const float* __restrict__ gamma, float* __restrict__ out) {
    const int tid  = threadIdx.x;
    const int lane = tid & 63;
    const int w    = tid >> 6;        // wave 0..3
    const int wm   = w & 1;           // wave row (0..1)
    const int wn   = w >> 1;          // wave col (0..1)

    const int bm = blockIdx.x & 63;   // fast-varying -> consecutive blocks
    const int bn = blockIdx.x >> 6;   //   share the B tile (L2 locality)
    const int row0 = bm * 128;
    const int col0 = bn * 128;

    f32x4 acc[4][4] = {};

    // fragment base: group (bm*8 + wm*4 + mi), window h, lane*32
    const unsigned char* abase = xs + (size_t)(bm * 8 + wm * 4) * 8192 + lane * 32;
    const unsigned char* bbase = ys + (size_t)(bn * 8 + wn * 4) * 8192 + lane * 32;

#pragma unroll 2
    for (int h = 0; h < 4; ++h) {
        i32x8 af[4], bfr[4];
#pragma unroll
        for (int mi = 0; mi < 4; ++mi) {
            const unsigned char* p = abase + mi * 8192 + h * 2048;
            i32x4 lo = *(const i32x4*)(p);
            i32x4 hi = *(const i32x4*)(p + 16);
            af[mi] = __builtin_shufflevector(lo, hi, 0, 1, 2, 3, 4, 5, 6, 7);
        }
#pragma unroll
        for (int ni = 0; ni < 4; ++ni) {
            const unsigned char* p = bbase + ni * 8192 + h * 2048;
            i32x4 lo = *(const i32x4*)(p);
            i32x4 hi = *(const i32x4*)(p + 16);
            bfr[ni] = __builtin_shufflevector(lo, hi, 0, 1, 2, 3, 4, 5, 6, 7);
        }
#pragma unroll
        for (int mi = 0; mi < 4; ++mi)
#pragma unroll
            for (int ni = 0; ni < 4; ++ni)
                acc[mi][ni] = __builtin_amdgcn_mfma_scale_f32_16x16x128_f8f6f4(
                    af[mi], bfr[ni], acc[mi][ni],
                    0, 0,          // cbsz/blgp = fp8 e4m3
                    0, 0x7F,       // A scale = 1.0 (E8M0 127)
                    0, 0x7F);      // B scale = 1.0
    }

    // Epilogue: out[r][c] = exp(-g*(x2[r]+y2[c]-2*xy))
    // C/D layout (16x16): col = lane&15, row = (lane>>4)*4 + reg.
    // Plain scalar stores; L2 write-back merges the 64 B segments into lines.
    const float g = gamma[0];
#pragma unroll
    for (int mi = 0; mi < 4; ++mi) {
        const int rbase = row0 + wm * 64 + mi * 16 + (lane >> 4) * 4;
        float xn[4];
#pragma unroll
        for (int r = 0; r < 4; ++r) xn[r] = x2[rbase + r];
#pragma unroll
        for (int ni = 0; ni < 4; ++ni) {
            const int col = col0 + wn * 64 + ni * 16 + (lane & 15);
            const float yn = y2[col];
            float* op = out + (size_t)rbase * OUTN + col;
#pragma unroll
            for (int r = 0; r < 4; ++r) {
                float s = xn[r] + yn - 2.0f * acc[mi][ni][r];
                op[(size_t)r * OUTN] = __expf(-g * s);
            }
        }
    }
}

extern "C" void kernel_launch(void* const* d_in, const int* in_sizes, int n_in,
                              void* d_out, int out_size, void* d_ws, size_t ws_size,
                              hipStream_t stream) {
    const float* x     = (const float*)d_in[0];
    const float* y     = (const float*)d_in[1];
    const float* gamma = (const float*)d_in[2];
    float* out = (float*)d_out;

    // workspace: xs (4 MB, swizzled fp8) | ys (4 MB) | x2 (32 KB) | y2 (32 KB)
    char* ws = (char*)d_ws;
    unsigned char* xs = (unsigned char*)ws;
    unsigned char* ys = (unsigned char*)(ws + (size_t)NROWS * DDIM);
    float* x2 = (float*)(ws + (size_t)NROWS * DDIM * 2);
    float* y2 = (float*)(ws + (size_t)NROWS * DDIM * 2 + NROWS * 4);

    rbf_prep<<<4096, 256, 0, stream>>>(x, y, xs, ys, x2, y2);
    rbf_gemm<<<4096, 256, 0, stream>>>(xs, ys, x2, y2, gamma, out);
}